// Round 1
// baseline (575.803 us; speedup 1.0000x reference)
//
#include <hip/hip_runtime.h>

#define T_LEN 2048
#define UNR 8

__device__ __forceinline__ float clampf(float x, float lo, float hi) {
    return fminf(fmaxf(x, lo), hi);
}

__global__ __launch_bounds__(64, 1)
void hirnn_kernel(const float* __restrict__ inp,
                  const float* __restrict__ pINSC, const float* __restrict__ pCOEFF,
                  const float* __restrict__ pSQ,   const float* __restrict__ pSMSC,
                  const float* __restrict__ pSUB,  const float* __restrict__ pCRAK,
                  const float* __restrict__ pRecK, const float* __restrict__ pKr,
                  const float* __restrict__ pLG,   const float* __restrict__ pLS,
                  float* __restrict__ out)
{
    const int b = blockIdx.x * blockDim.x + threadIdx.x;

    // ---- wave-uniform parameter prep (reference clip semantics) ----
    const float insc = clampf(pINSC[0] * 5.f,   0.5f,   5.f);
    const float C    = clampf(pCOEFF[0] * 400.f, 50.f,  400.f);
    const float q    = clampf(pSQ[0] * 6.f,     0.f,    6.f);
    const float S    = clampf(pSMSC[0] * 500.f, 50.f,   500.f);
    const float sub  = clampf(pSUB[0],          0.f,    1.f);
    const float crak = clampf(pCRAK[0],         0.f,    1.f);
    const float rk   = clampf(pRecK[0] * 0.3f,  0.003f, 0.3f);
    const float kr   = clampf(pKr[0] * 0.1f,    0.01f,  0.1f);
    const float lg   = clampf(pLG[0] * 0.1f,    0.001f, 0.1f);
    const float ls   = clampf(pLS[0] * 10.f,    0.01f,  10.f);
    const float invS = 1.0f / S;
    const float eca  = -q * invS;   // infil = C * exp(eca * SMS1c)

    const float4* __restrict__ xin  = reinterpret_cast<const float4*>(inp) + (size_t)b * T_LEN;
    float4* __restrict__       qout = reinterpret_cast<float4*>(out + (size_t)b * T_LEN);

    float sms = 0.f, gw = 0.f, rs = 0.f;          // scan state
    float p0 = 0.f, pet0 = 0.f, rsm0 = 0.f, ar0 = 0.f, rs0 = 0.f;  // t==0 saves

    float4 bufA[UNR], bufB[UNR];
#pragma unroll
    for (int u = 0; u < UNR; ++u) bufA[u] = xin[u];

    auto process = [&](const float4* buf, int t0) {
        float qstage[UNR];
#pragma unroll
        for (int u = 0; u < UNR; ++u) {
            const float p = buf[u].x, pet = buf[u].y, rsmax = buf[u].z, area = buf[u].w;

            // ---- interception ----
            const float INT  = fminf(fminf(insc, pet), p);   // all operands >= 0
            const float INR  = p - INT;                      // exact >= 0
            // ---- sms store + soil fluxes ----
            const float smsc  = fminf(fmaxf(sms, 0.f), S);
            const float ratio = smsc * invS;
            const float infil = C * __expf(eca * smsc);
            const float RMO   = fminf(infil, INR);           // H-pair == min (exact at tie)
            const float IRUN  = INR - RMO;
            const float SRUN  = sub * ratio * RMO;
            const float REC   = crak * ratio * (RMO - SRUN);
            const float SMF   = (RMO - SRUN) - REC;
            const float POT   = fmaxf(pet - INT, 0.f);
            const float ETS   = fminf(POT, 10.f * ratio);    // H-pair == min
            // ---- recharge + state updates (clips provably non-binding) ----
            const float nsms  = smsc + (SMF - ETS);
            const float RECn  = REC + fmaxf(nsms - S, 0.f);
            const float BAS   = rk * fmaxf(gw, 0.f);         // H(gw)*rk*gw
            const float ngw   = (gw - lg) + (RECn - BAS);
            // ---- release (scan step: uses pre-step rs) ----
            const float inflow = (IRUN + SRUN + BAS) * area; // >= 0
            const float rinv   = __builtin_amdgcn_rcpf(rsmax);
            const float xr     = (rs + inflow) - rsmax;
            const float Qor    = fmaxf(xr, 0.f);
            const float rrt    = rs * rinv;
            const float Qir    = (xr > 0.f) ? (kr * rsmax)
                                            : (kr * rs * (rrt * __builtin_amdgcn_sqrtf(rrt)));
            const float nrs    = rs + ((inflow - Qor) - Qir);

            // ---- fused post-pass for this t (valid for t>=1; t==0 fixed in epilogue) ----
            // SMS1[t]=pre-step sms, GW1[t]=pre-step gw -> INT/INR/IRUN/SRUN/BAS/inflow reusable;
            // only _release differs: it uses post-step RS (nrs).
            const float xq   = (nrs + inflow) - rsmax;
            const float Qor2 = fmaxf(xq, 0.f);
            const float r2   = nrs * rinv;
            const float Qir2 = (xq > 0.f) ? (kr * rsmax)
                                          : (kr * nrs * (r2 * __builtin_amdgcn_sqrtf(r2)));
            const float oma  = 1.f - area;
            const float dra  = (SRUN + IRUN) * oma + Qir2 + Qor2 - ls;
            qstage[u] = fmaxf(fmaxf(dra, 0.f) + BAS * oma, 0.f);

            if (t0 == 0 && u == 0) { p0 = p; pet0 = pet; rsm0 = rsmax; ar0 = area; rs0 = nrs; }
            sms = nsms; gw = ngw; rs = nrs;
        }
#pragma unroll
        for (int v = 0; v < UNR / 4; ++v) {
            float4 w;
            w.x = qstage[4*v + 0]; w.y = qstage[4*v + 1];
            w.z = qstage[4*v + 2]; w.w = qstage[4*v + 3];
            qout[t0 / 4 + v] = w;
        }
    };

    // ping-pong register prefetch: group g+1 loads in flight while group g computes
    for (int t0 = 0; t0 < T_LEN; t0 += 2 * UNR) {
#pragma unroll
        for (int u = 0; u < UNR; ++u) bufB[u] = xin[t0 + UNR + u];
        process(bufA, t0);
        if (t0 + 2 * UNR < T_LEN) {
#pragma unroll
            for (int u = 0; u < UNR; ++u) bufA[u] = xin[t0 + 2 * UNR + u];
        }
        process(bufB, t0 + UNR);
    }

    // ---- epilogue: t == 0 uses SMS1[0]=final sms, GW1[0]=final gw, RS[0]=rs after step 0 ----
    {
        const float INT   = fminf(fminf(insc, pet0), p0);
        const float INR   = p0 - INT;
        const float smsc  = fminf(fmaxf(sms, 0.f), S);
        const float ratio = smsc * invS;
        const float infil = C * __expf(eca * smsc);
        const float RMO   = fminf(infil, INR);
        const float IRUN  = INR - RMO;
        const float SRUN  = sub * ratio * RMO;
        const float BAS   = rk * fmaxf(gw, 0.f);
        const float inflow = (IRUN + SRUN + BAS) * ar0;
        const float rinv   = __builtin_amdgcn_rcpf(rsm0);
        const float xq     = (rs0 + inflow) - rsm0;
        const float Qor2   = fmaxf(xq, 0.f);
        const float r2     = rs0 * rinv;
        const float Qir2   = (xq > 0.f) ? (kr * rsm0)
                                        : (kr * rs0 * (r2 * __builtin_amdgcn_sqrtf(r2)));
        const float oma    = 1.f - ar0;
        const float dra    = (SRUN + IRUN) * oma + Qir2 + Qor2 - ls;
        out[(size_t)b * T_LEN] = fmaxf(fmaxf(dra, 0.f) + BAS * oma, 0.f);
    }
}

extern "C" void kernel_launch(void* const* d_in, const int* in_sizes, int n_in,
                              void* d_out, int out_size, void* d_ws, size_t ws_size,
                              hipStream_t stream) {
    const float* inp = (const float*)d_in[0];
    const int B = in_sizes[0] / (T_LEN * 4);   // 4096
    dim3 grid(B / 64), block(64);
    hirnn_kernel<<<grid, block, 0, stream>>>(
        inp,
        (const float*)d_in[1],  // INSC
        (const float*)d_in[2],  // COEFF
        (const float*)d_in[3],  // SQ
        (const float*)d_in[4],  // SMSC
        (const float*)d_in[5],  // SUB
        (const float*)d_in[6],  // CRAK
        (const float*)d_in[7],  // RecK
        (const float*)d_in[8],  // Kr
        (const float*)d_in[9],  // LG
        (const float*)d_in[10], // LS
        (float*)d_out);
}

// Round 2
// 307.785 us; speedup vs baseline: 1.8708x; 1.8708x over previous
//
#include <hip/hip_runtime.h>

#define T_LEN  2048
#define NCH    4096     // chains (B)
#define CH     64       // chunk length (timesteps per output chunk)
#define NCHUNK (T_LEN / CH)
#define WARM   256      // warm-up steps before each chunk (chunk 0: exact from zero)
#define UNR    8

__device__ __forceinline__ float clampf(float x, float lo, float hi) {
    return fminf(fmaxf(x, lo), hi);
}

struct Params {
    float insc, C, S, sub, crak, rk, kr, lg, ls, invS, eca;
};

__device__ __forceinline__ Params mkparams(
    const float* pINSC, const float* pCOEFF, const float* pSQ, const float* pSMSC,
    const float* pSUB, const float* pCRAK, const float* pRecK, const float* pKr,
    const float* pLG, const float* pLS)
{
    Params pr;
    pr.insc = clampf(pINSC[0] * 5.f,   0.5f,   5.f);
    pr.C    = clampf(pCOEFF[0] * 400.f, 50.f,  400.f);
    float q = clampf(pSQ[0] * 6.f,     0.f,    6.f);
    pr.S    = clampf(pSMSC[0] * 500.f, 50.f,   500.f);
    pr.sub  = clampf(pSUB[0],          0.f,    1.f);
    pr.crak = clampf(pCRAK[0],         0.f,    1.f);
    pr.rk   = clampf(pRecK[0] * 0.3f,  0.003f, 0.3f);
    pr.kr   = clampf(pKr[0] * 0.1f,    0.01f,  0.1f);
    pr.lg   = clampf(pLG[0] * 0.1f,    0.001f, 0.1f);
    pr.ls   = clampf(pLS[0] * 10.f,    0.01f,  10.f);
    pr.invS = 1.0f / pr.S;
    pr.eca  = -q * pr.invS;
    return pr;
}

// ---------------- main chunked scan kernel ----------------
__global__ __launch_bounds__(256, 2)
void hirnn_chunk_kernel(const float* __restrict__ inp,
                        const float* __restrict__ pINSC, const float* __restrict__ pCOEFF,
                        const float* __restrict__ pSQ,   const float* __restrict__ pSMSC,
                        const float* __restrict__ pSUB,  const float* __restrict__ pCRAK,
                        const float* __restrict__ pRecK, const float* __restrict__ pKr,
                        const float* __restrict__ pLG,   const float* __restrict__ pLS,
                        float* __restrict__ out, float* __restrict__ ws)
{
    const int tid   = blockIdx.x * blockDim.x + threadIdx.x;
    const int chain = tid & (NCH - 1);     // lanes of a wave = consecutive chains
    const int chunk = tid >> 12;           // wave-uniform (4096 chains per chunk)

    const Params pr = mkparams(pINSC, pCOEFF, pSQ, pSMSC, pSUB, pCRAK, pRecK, pKr, pLG, pLS);

    const float4* __restrict__ xin  = reinterpret_cast<const float4*>(inp) + (size_t)chain * T_LEN;
    float4* __restrict__       qout = reinterpret_cast<float4*>(out + (size_t)chain * T_LEN);

    const int t_start = chunk * CH;
    const int t_warm  = (t_start >= WARM) ? (t_start - WARM) : 0;
    const int t_end   = t_start + CH;

    float sms = 0.f, gw = 0.f, rs = 0.f;   // warm-start from zero state

    float4 bufA[UNR], bufB[UNR];
#pragma unroll
    for (int u = 0; u < UNR; ++u) bufA[u] = xin[t_warm + u];

    auto process = [&](const float4* buf, int t0) {
        float qstage[UNR];
#pragma unroll
        for (int u = 0; u < UNR; ++u) {
            const float p = buf[u].x, pet = buf[u].y, rsmax = buf[u].z, area = buf[u].w;

            const float INT  = fminf(fminf(pr.insc, pet), p);
            const float INR  = p - INT;
            const float smsc  = fminf(fmaxf(sms, 0.f), pr.S);
            const float ratio = smsc * pr.invS;
            const float infil = pr.C * __expf(pr.eca * smsc);
            const float RMO   = fminf(infil, INR);
            const float IRUN  = INR - RMO;
            const float SRUN  = pr.sub * ratio * RMO;
            const float REC   = pr.crak * ratio * (RMO - SRUN);
            const float SMF   = (RMO - SRUN) - REC;
            const float POT   = fmaxf(pet - INT, 0.f);
            const float ETS   = fminf(POT, 10.f * ratio);
            const float nsms  = smsc + (SMF - ETS);
            const float RECn  = REC + fmaxf(nsms - pr.S, 0.f);
            const float BAS   = pr.rk * fmaxf(gw, 0.f);
            const float ngw   = (gw - pr.lg) + (RECn - BAS);
            const float inflow = (IRUN + SRUN + BAS) * area;
            const float rinv   = __builtin_amdgcn_rcpf(rsmax);
            const float xr     = (rs + inflow) - rsmax;
            const float Qor    = fmaxf(xr, 0.f);
            const float rrt    = rs * rinv;
            const float Qir    = (xr > 0.f) ? (pr.kr * rsmax)
                                            : (pr.kr * rs * (rrt * __builtin_amdgcn_sqrtf(rrt)));
            const float nrs    = rs + ((inflow - Qor) - Qir);

            // fused post-pass (valid for t>=1; t==0 fixed by hirnn_t0_kernel)
            const float xq   = (nrs + inflow) - rsmax;
            const float Qor2 = fmaxf(xq, 0.f);
            const float r2   = nrs * rinv;
            const float Qir2 = (xq > 0.f) ? (pr.kr * rsmax)
                                          : (pr.kr * nrs * (r2 * __builtin_amdgcn_sqrtf(r2)));
            const float oma  = 1.f - area;
            const float dra  = (SRUN + IRUN) * oma + Qir2 + Qor2 - pr.ls;
            qstage[u] = fmaxf(fmaxf(dra, 0.f) + BAS * oma, 0.f);

            sms = nsms; gw = ngw; rs = nrs;
        }
        if (t0 >= t_start) {           // wave-uniform; group-aligned (WARM,CH mult of 16)
#pragma unroll
            for (int v = 0; v < UNR / 4; ++v) {
                float4 w;
                w.x = qstage[4*v + 0]; w.y = qstage[4*v + 1];
                w.z = qstage[4*v + 2]; w.w = qstage[4*v + 3];
                qout[t0 / 4 + v] = w;
            }
        }
    };

    for (int t0 = t_warm; t0 < t_end; t0 += 2 * UNR) {
#pragma unroll
        for (int u = 0; u < UNR; ++u) bufB[u] = xin[t0 + UNR + u];
        process(bufA, t0);
        if (t0 + 2 * UNR < t_end) {
#pragma unroll
            for (int u = 0; u < UNR; ++u) bufA[u] = xin[t0 + 2 * UNR + u];
        }
        process(bufB, t0 + UNR);
    }

    if (chunk == NCHUNK - 1) {         // final state for the t==0 fix-up
        ws[chain * 2 + 0] = sms;
        ws[chain * 2 + 1] = gw;
    }
}

// ---------------- t == 0 fix-up kernel ----------------
// Q[b,0] uses SMS1=final sms, GW1=final gw, RS=rs after step 0 (exact: zero start state).
__global__ __launch_bounds__(256)
void hirnn_t0_kernel(const float* __restrict__ inp,
                     const float* __restrict__ pINSC, const float* __restrict__ pCOEFF,
                     const float* __restrict__ pSQ,   const float* __restrict__ pSMSC,
                     const float* __restrict__ pSUB,  const float* __restrict__ pCRAK,
                     const float* __restrict__ pRecK, const float* __restrict__ pKr,
                     const float* __restrict__ pLG,   const float* __restrict__ pLS,
                     const float* __restrict__ ws, float* __restrict__ out)
{
    const int b = blockIdx.x * blockDim.x + threadIdx.x;
    if (b >= NCH) return;

    const Params pr = mkparams(pINSC, pCOEFF, pSQ, pSMSC, pSUB, pCRAK, pRecK, pKr, pLG, pLS);

    const float4 x0 = reinterpret_cast<const float4*>(inp)[(size_t)b * T_LEN];
    const float p = x0.x, pet = x0.y, rsmax = x0.z, area = x0.w;

    const float INT = fminf(fminf(pr.insc, pet), p);
    const float INR = p - INT;

    // RS after step 0, exact from zero state: sms=0 -> ratio=0, infil=C; gw=0 -> BAS0=0
    const float RMO0   = fminf(pr.C, INR);
    const float IRUN0  = INR - RMO0;
    const float infl0  = IRUN0 * area;
    const float xr0    = infl0 - rsmax;
    const float Qor0   = fmaxf(xr0, 0.f);
    const float Qir0   = (xr0 > 0.f) ? (pr.kr * rsmax) : 0.f;   // rs=0 -> power term = 0
    const float rs0    = infl0 - Qor0 - Qir0;

    // post-pass with SMS1 = final sms, GW1 = final gw
    const float smsF  = ws[b * 2 + 0];
    const float gwF   = ws[b * 2 + 1];
    const float smsc  = fminf(fmaxf(smsF, 0.f), pr.S);
    const float ratio = smsc * pr.invS;
    const float infil = pr.C * __expf(pr.eca * smsc);
    const float RMO   = fminf(infil, INR);
    const float IRUN  = INR - RMO;
    const float SRUN  = pr.sub * ratio * RMO;
    const float BAS   = pr.rk * fmaxf(gwF, 0.f);

    const float inflow = (IRUN + SRUN + BAS) * area;
    const float rinv   = __builtin_amdgcn_rcpf(rsmax);
    const float xq     = (rs0 + inflow) - rsmax;
    const float Qor2   = fmaxf(xq, 0.f);
    const float r2     = rs0 * rinv;
    const float Qir2   = (xq > 0.f) ? (pr.kr * rsmax)
                                    : (pr.kr * rs0 * (r2 * __builtin_amdgcn_sqrtf(r2)));
    const float oma    = 1.f - area;
    const float dra    = (SRUN + IRUN) * oma + Qir2 + Qor2 - pr.ls;
    out[(size_t)b * T_LEN] = fmaxf(fmaxf(dra, 0.f) + BAS * oma, 0.f);
}

extern "C" void kernel_launch(void* const* d_in, const int* in_sizes, int n_in,
                              void* d_out, int out_size, void* d_ws, size_t ws_size,
                              hipStream_t stream) {
    const float* inp = (const float*)d_in[0];
    float* out = (float*)d_out;
    float* ws  = (float*)d_ws;   // 4096 * 2 floats

    const int threads = NCH * NCHUNK;           // 131072
    hirnn_chunk_kernel<<<threads / 256, 256, 0, stream>>>(
        inp,
        (const float*)d_in[1], (const float*)d_in[2], (const float*)d_in[3],
        (const float*)d_in[4], (const float*)d_in[5], (const float*)d_in[6],
        (const float*)d_in[7], (const float*)d_in[8], (const float*)d_in[9],
        (const float*)d_in[10],
        out, ws);

    hirnn_t0_kernel<<<NCH / 256, 256, 0, stream>>>(
        inp,
        (const float*)d_in[1], (const float*)d_in[2], (const float*)d_in[3],
        (const float*)d_in[4], (const float*)d_in[5], (const float*)d_in[6],
        (const float*)d_in[7], (const float*)d_in[8], (const float*)d_in[9],
        (const float*)d_in[10],
        ws, out);
}